// Round 1
// baseline (154.043 us; speedup 1.0000x reference)
//
#include <hip/hip_runtime.h>
#include <stdint.h>
#include <math.h>

#pragma clang fp contract(off)

#define N_ROWS 1048576
#define N_CLS  20
#define K_TOP  2000
#define SORT_N 2048

// scalar slots
#define SC_B0  0
#define SC_R1  1
#define SC_T16 2
#define SC_R2  3
#define SC_T24 4   // final threshold T on (mkey>>8)
#define SC_CNT 5

// ws layout
static constexpr size_t OFF_MKEY  = 0;                          // u32[N]
static constexpr size_t OFF_CLS   = OFF_MKEY + 4ull * N_ROWS;   // u8[N]
static constexpr size_t OFF_HIST1 = OFF_CLS + (size_t)N_ROWS;   // u32[256]
static constexpr size_t OFF_HIST2 = OFF_HIST1 + 1024;
static constexpr size_t OFF_HIST3 = OFF_HIST2 + 1024;
static constexpr size_t OFF_SCAL  = OFF_HIST3 + 1024;           // u32[16]
static constexpr size_t OFF_GRP   = OFF_SCAL + 64;              // u64[32]
static constexpr size_t OFF_CAND  = OFF_GRP + 256;              // u64[SORT_N]
static constexpr size_t OFF_BNMS  = OFF_CAND + 8ull * SORT_N;   // float4[2048]
static constexpr size_t OFF_MASK  = OFF_BNMS + 16ull * 2048;    // u64[K_TOP*32]

__device__ __forceinline__ uint32_t mono_key(float f) {
    uint32_t u = __float_as_uint(f);
    return u ^ ((u & 0x80000000u) ? 0xFFFFFFFFu : 0x80000000u);
}
__device__ __forceinline__ float mono_inv(uint32_t k) {
    uint32_t u = (k & 0x80000000u) ? (k ^ 0x80000000u) : ~k;
    return __uint_as_float(u);
}

// ---- K1: per-row max/argmax of logits, store monotone key + class; fused hist over key>>24
__global__ __launch_bounds__(256) void k_score(const float* __restrict__ logits,
                                               uint32_t* __restrict__ mkey,
                                               uint8_t* __restrict__ cls,
                                               uint32_t* __restrict__ hist1) {
    __shared__ uint32_t h[256];
    h[threadIdx.x] = 0;
    __syncthreads();
    int base = blockIdx.x * 1024 + threadIdx.x;
    for (int k = 0; k < 4; ++k) {
        int row = base + k * 256;
        const float4* p = (const float4*)(logits + (size_t)row * N_CLS);
        float v[20];
#pragma unroll
        for (int q = 0; q < 5; ++q) {
            float4 t = p[q];
            v[4 * q + 0] = t.x; v[4 * q + 1] = t.y; v[4 * q + 2] = t.z; v[4 * q + 3] = t.w;
        }
        float m = v[0]; int ci = 0;
#pragma unroll
        for (int c = 1; c < 20; ++c) { if (v[c] > m) { m = v[c]; ci = c; } }
        uint32_t u = mono_key(m);
        mkey[row] = u;
        cls[row] = (uint8_t)ci;
        atomicAdd(&h[u >> 24], 1u);
    }
    __syncthreads();
    uint32_t hv = h[threadIdx.x];
    if (hv) atomicAdd(&hist1[threadIdx.x], hv);
}

// ---- find threshold byte from a 256-bin histogram (serial, cheap)
__global__ void k_find(const uint32_t* __restrict__ hist, uint32_t* __restrict__ scal, int phase) {
    if (threadIdx.x != 0 || blockIdx.x != 0) return;
    uint32_t target = (phase == 0) ? (uint32_t)K_TOP : scal[(phase == 1) ? SC_R1 : SC_R2];
    uint32_t cum = 0; int b = 255;
    for (; b >= 0; --b) { cum += hist[b]; if (cum >= target) break; }
    if (b < 0) b = 0;
    uint32_t above = cum - hist[b];
    uint32_t need = (target > above) ? (target - above) : 1u;
    if (phase == 0) { scal[SC_B0] = (uint32_t)b; scal[SC_R1] = need; }
    else if (phase == 1) { scal[SC_T16] = (scal[SC_B0] << 8) | (uint32_t)b; scal[SC_R2] = need; }
    else {
        uint32_t t24 = (scal[SC_T16] << 8) | (uint32_t)b;
        scal[SC_T24] = (t24 > 0) ? (t24 - 1) : 0;  // -1 bin safety: covers rounded-score ties
    }
}

// ---- restricted byte histogram (phase 1: bits23:16 where top byte==b0; phase 2: bits15:8 where top16==t16)
__global__ __launch_bounds__(256) void k_hist(const uint32_t* __restrict__ mkey,
                                              const uint32_t* __restrict__ scal,
                                              uint32_t* __restrict__ hist, int phase) {
    __shared__ uint32_t h[256];
    h[threadIdx.x] = 0;
    __syncthreads();
    uint32_t pfx = (phase == 1) ? scal[SC_B0] : scal[SC_T16];
    int base = blockIdx.x * 1024 + threadIdx.x;
    for (int k = 0; k < 4; ++k) {
        uint32_t u = mkey[base + k * 256];
        if (phase == 1) { if ((u >> 24) == pfx) atomicAdd(&h[(u >> 16) & 0xFFu], 1u); }
        else            { if ((u >> 16) == pfx) atomicAdd(&h[(u >> 8) & 0xFFu], 1u); }
    }
    __syncthreads();
    uint32_t hv = h[threadIdx.x];
    if (hv) atomicAdd(&hist[threadIdx.x], hv);
}

// ---- compact candidates (mkey>>8 >= T)
__global__ __launch_bounds__(256) void k_compact(const uint32_t* __restrict__ mkey,
                                                 uint32_t* __restrict__ scal,
                                                 uint64_t* __restrict__ cand) {
    uint32_t T = scal[SC_T24];
    int base = blockIdx.x * 1024 + threadIdx.x;
    for (int k = 0; k < 4; ++k) {
        int row = base + k * 256;
        uint32_t u = mkey[row];
        if ((u >> 8) >= T) {
            uint32_t pos = atomicAdd(&scal[SC_CNT], 1u);
            if (pos < (uint32_t)SORT_N) cand[pos] = ((uint64_t)u << 32) | (uint32_t)row;
        }
    }
}

// ---- single-block: sigmoid for candidates, bitonic sort by (score desc, idx asc),
//      decode boxes, write outputs, reduce max_coord, build offset boxes for NMS
__global__ __launch_bounds__(1024) void k_sort(const uint64_t* __restrict__ cand,
                                               const uint32_t* __restrict__ scal,
                                               const float* __restrict__ deltas,
                                               const float* __restrict__ locs,
                                               const int* __restrict__ stridep,
                                               const uint8_t* __restrict__ cls,
                                               float* __restrict__ out,
                                               float4* __restrict__ bnms) {
    __shared__ uint64_t keys[SORT_N];
    __shared__ float boxes[K_TOP * 4];
    __shared__ uint8_t ucls[K_TOP];
    __shared__ float red[16];
    int tid = threadIdx.x;
    uint32_t M = scal[SC_CNT];
    if (M > (uint32_t)SORT_N) M = SORT_N;

    for (int t = tid; t < SORT_N; t += 1024) {
        if (t < (int)M) {
            uint64_t cd = cand[t];
            uint32_t mk = (uint32_t)(cd >> 32);
            uint32_t idx = (uint32_t)cd;
            float m = mono_inv(mk);
            float ef = (float)exp(-(double)m);        // ~correctly-rounded fp32 expf
            float s = 1.0f / (1.0f + ef);
            keys[t] = ((uint64_t)(~__float_as_uint(s)) << 32) | idx;
        } else {
            keys[t] = ~0ull;
        }
    }
    __syncthreads();
    for (int k = 2; k <= SORT_N; k <<= 1) {
        for (int j = k >> 1; j > 0; j >>= 1) {
            for (int t = tid; t < SORT_N; t += 1024) {
                int ixj = t ^ j;
                if (ixj > t) {
                    uint64_t a = keys[t], b = keys[ixj];
                    bool up = ((t & k) == 0);
                    if ((a > b) == up) { keys[t] = b; keys[ixj] = a; }
                }
            }
            __syncthreads();
        }
    }

    float stridef = (float)(*stridep);
    for (int r = tid; r < K_TOP; r += 1024) {
        uint64_t key = keys[r];
        uint32_t idx = (uint32_t)(key & 0xFFFFFFFFull);
        idx &= (N_ROWS - 1);                          // OOB safety
        uint32_t sbits = ~(uint32_t)(key >> 32);
        float s = __uint_as_float(sbits);
        float4 dl = ((const float4*)deltas)[idx];
        float2 lc = ((const float2*)locs)[idx];
        float d0 = dl.x * stridef, d1 = dl.y * stridef, d2 = dl.z * stridef, d3 = dl.w * stridef;
        float b0 = lc.x - d0, b1 = lc.y - d1, b2 = lc.x + d2, b3 = lc.y + d3;
        out[4 * r + 0] = b0; out[4 * r + 1] = b1; out[4 * r + 2] = b2; out[4 * r + 3] = b3;
        out[8000 + r] = s;
        uint8_t c = cls[idx];
        out[10000 + r] = (float)c;
        boxes[4 * r + 0] = b0; boxes[4 * r + 1] = b1; boxes[4 * r + 2] = b2; boxes[4 * r + 3] = b3;
        ucls[r] = c;
    }
    __syncthreads();
    // block max over 8000 box coords
    float mx = -3.4e38f;
    for (int t = tid; t < K_TOP * 4; t += 1024) mx = fmaxf(mx, boxes[t]);
    for (int o = 32; o > 0; o >>= 1) mx = fmaxf(mx, __shfl_down(mx, o));
    if ((tid & 63) == 0) red[tid >> 6] = mx;
    __syncthreads();
    if (tid == 0) {
        float m2 = red[0];
        for (int i = 1; i < 16; ++i) m2 = fmaxf(m2, red[i]);
        red[0] = m2 + 1.0f;                           // max_coord + 1
    }
    __syncthreads();
    float off1 = red[0];
    for (int r = tid; r < K_TOP; r += 1024) {
        float o = (float)ucls[r] * off1;
        float4 b;
        b.x = boxes[4 * r + 0] + o;
        b.y = boxes[4 * r + 1] + o;
        b.z = boxes[4 * r + 2] + o;
        b.w = boxes[4 * r + 3] + o;
        bnms[r] = b;
    }
}

// ---- pairwise suppression mask (quirky IoU replicated exactly)
__global__ __launch_bounds__(256) void k_mask(const float4* __restrict__ bnms,
                                              uint64_t* __restrict__ mask,
                                              unsigned long long* __restrict__ grp) {
    int wave = (int)((blockIdx.x * 256 + threadIdx.x) >> 6);
    int lane = threadIdx.x & 63;
    int i = wave >> 5;
    int jb = wave & 31;
    int j = jb * 64 + lane;
    float4 bi = bnms[i];
    bool sup = false;
    if (j < K_TOP && j > i) {
        float4 bj = bnms[j];
        float x1i = bi.x, y1i = bi.w, x2i = bi.z, y2i = bi.y;
        float x1j = bj.x, y1j = bj.w, x2j = bj.z, y2j = bj.y;
        float ai = (x2i - x1i) * (y2i - y1i);
        float aj = (x2j - x1j) * (y2j - y1j);
        float xx1 = fmaxf(x1i, x1j);
        float yy1 = fminf(y1i, y1j);
        float xx2 = fminf(x2i, x2j);
        float yy2 = fmaxf(y2i, y2j);
        float inter = fabsf(xx2 - xx1) * fabsf(yy2 - yy1);
        float iou = inter / ((ai + aj) - inter);
        sup = iou > 0.5f;
    }
    unsigned long long bits = __ballot(sup);
    if (lane == 0) {
        mask[(size_t)i * 32 + jb] = bits;
        if (bits) atomicOr(&grp[i >> 6], 1ull << (i & 63));
    }
}

// ---- sequential NMS scan over nonzero-mask rows only; final active == keep
__global__ void k_scan(const uint64_t* __restrict__ mask,
                       const unsigned long long* __restrict__ grp,
                       float* __restrict__ out) {
    int lane = threadIdx.x;  // 64 threads, lane w<32 holds active word w
    uint64_t active = ~0ull;
    for (int g = 0; g < 32; ++g) {
        unsigned long long nz = grp[g];
        while (nz) {
            int b = __ffsll((long long)nz) - 1;
            nz &= nz - 1;
            int i = g * 64 + b;
            uint64_t aw = __shfl(active, g);
            bool kept = (aw >> b) & 1ull;
            uint64_t m = (lane < 32) ? mask[(size_t)i * 32 + lane] : 0ull;
            if (kept) active &= ~m;
        }
    }
    if (lane < 32) {
        for (int b = 0; b < 64; ++b) {
            int j = lane * 64 + b;
            if (j < K_TOP) out[12000 + j] = ((active >> b) & 1ull) ? 1.0f : 0.0f;
        }
    }
}

extern "C" void kernel_launch(void* const* d_in, const int* in_sizes, int n_in,
                              void* d_out, int out_size, void* d_ws, size_t ws_size,
                              hipStream_t stream) {
    const float* deltas = (const float*)d_in[0];
    const float* locs   = (const float*)d_in[1];
    const float* logits = (const float*)d_in[2];
    const int*   stridep = (const int*)d_in[3];
    float* out = (float*)d_out;
    char* ws = (char*)d_ws;

    uint32_t* mkey  = (uint32_t*)(ws + OFF_MKEY);
    uint8_t*  cls   = (uint8_t*)(ws + OFF_CLS);
    uint32_t* hist1 = (uint32_t*)(ws + OFF_HIST1);
    uint32_t* hist2 = (uint32_t*)(ws + OFF_HIST2);
    uint32_t* hist3 = (uint32_t*)(ws + OFF_HIST3);
    uint32_t* scal  = (uint32_t*)(ws + OFF_SCAL);
    unsigned long long* grp = (unsigned long long*)(ws + OFF_GRP);
    uint64_t* cand  = (uint64_t*)(ws + OFF_CAND);
    float4*   bnms  = (float4*)(ws + OFF_BNMS);
    uint64_t* mask  = (uint64_t*)(ws + OFF_MASK);

    // zero hists + scalars + group flags (re-zeroed every call for determinism)
    hipMemsetAsync(ws + OFF_HIST1, 0, OFF_CAND - OFF_HIST1, stream);

    k_score<<<dim3(1024), dim3(256), 0, stream>>>(logits, mkey, cls, hist1);
    k_find<<<dim3(1), dim3(64), 0, stream>>>(hist1, scal, 0);
    k_hist<<<dim3(1024), dim3(256), 0, stream>>>(mkey, scal, hist2, 1);
    k_find<<<dim3(1), dim3(64), 0, stream>>>(hist2, scal, 1);
    k_hist<<<dim3(1024), dim3(256), 0, stream>>>(mkey, scal, hist3, 2);
    k_find<<<dim3(1), dim3(64), 0, stream>>>(hist3, scal, 2);
    k_compact<<<dim3(1024), dim3(256), 0, stream>>>(mkey, scal, cand);
    k_sort<<<dim3(1), dim3(1024), 0, stream>>>(cand, scal, deltas, locs, stridep, cls, out, bnms);
    k_mask<<<dim3((K_TOP * 32) / 4), dim3(256), 0, stream>>>(bnms, mask, grp);
    k_scan<<<dim3(1), dim3(64), 0, stream>>>(mask, grp, out);
}